// Round 5
// baseline (1546.064 us; speedup 1.0000x reference)
//
#include <hip/hip_runtime.h>

#define NN 50000
#define NE 1600000
#define CLAMP_V 5.0f

typedef __attribute__((ext_vector_type(4))) short bf16x4;
typedef __attribute__((ext_vector_type(4))) float f32x4;

static __device__ __forceinline__ short f2bf(float x) {
    unsigned u = __builtin_bit_cast(unsigned, x);
    u += 0x7FFF + ((u >> 16) & 1);   // round-to-nearest-even
    return (short)(u >> 16);
}

__global__ __launch_bounds__(256) void proj_kernel(
    const float* __restrict__ x,
    const float* __restrict__ WQ, const float* __restrict__ bQ,
    const float* __restrict__ WK, const float* __restrict__ WVw,
    float* __restrict__ Q, float* __restrict__ K, float* __restrict__ V)
{
    __shared__ float sWQ[4096], sWK[4096], sWV[4096];
    for (int i = threadIdx.x; i < 4096; i += 256) {
        sWQ[i] = WQ[i]; sWK[i] = WK[i]; sWV[i] = WVw[i];
    }
    __syncthreads();
    const int col = threadIdx.x & 63;
    const int nl  = threadIdx.x >> 6;
    const float bq = bQ[col];
    for (int node = blockIdx.x * 4 + nl; node < NN; node += gridDim.x * 4) {
        const float* xr = x + (size_t)node * 64;
        float aq = 0.f, ak = 0.f, av = 0.f;
        #pragma unroll
        for (int j = 0; j < 64; ++j) {
            float xv = xr[j];
            aq = fmaf(xv, sWQ[j*64+col], aq);
            ak = fmaf(xv, sWK[j*64+col], ak);
            av = fmaf(xv, sWV[j*64+col], av);
        }
        Q[(size_t)node*64+col] = aq + bq;
        K[(size_t)node*64+col] = ak;
        V[(size_t)node*64+col] = av;
    }
}

// Fused edge pass, 4-edges-in-parallel float4 scoring:
//  E = edge_attr @ WE1 + bE1 (MFMA), sc = K[src]*Q[dst]*E -> wE,
//  ex = exp(clamp(sum_head(sc)/sqrt8)), den[dst,h] += ex (atomic),
//  Num[dst,c] += ex*(V[src,c]+sc)      (atomic, division deferred)
__global__ __launch_bounds__(256) void edge_fused_kernel(
    const float* __restrict__ edge_attr,
    const float* __restrict__ WE1, const float* __restrict__ bE1,
    const int* __restrict__ ei,
    const float* __restrict__ Q, const float* __restrict__ K,
    const float* __restrict__ V,
    float* __restrict__ wE, float* __restrict__ den, float* __restrict__ Num)
{
    __shared__ float Elds[4][16 * 68];   // row stride 68 floats (16B-aligned rows)
    const int tid  = threadIdx.x;
    const int wv   = tid >> 6;
    const int lane = tid & 63;
    const int g    = lane >> 4;      // k-group 0..3 (MFMA) / edge-quad (scoring)
    const int rowl = lane & 15;      // A-row (MFMA) / col-quad (scoring)

    // B fragments of WE1 (bf16) + bias. B[k=(ks*16 + g*4 + j)][col]
    bf16x4 bF[4][4];
    float  bias[4];
    #pragma unroll
    for (int cb = 0; cb < 4; ++cb) {
        const int col = rowl + 16 * cb;
        bias[cb] = bE1[col];
        #pragma unroll
        for (int ks = 0; ks < 4; ++ks) {
            bf16x4 t;
            #pragma unroll
            for (int j = 0; j < 4; ++j)
                t[j] = f2bf(WE1[(ks * 16 + g * 4 + j) * 64 + col]);
            bF[cb][ks] = t;
        }
    }

    const float inv_sqrt8 = 0.35355339059327373f;

    for (int tile = blockIdx.x; tile < (NE / 64); tile += gridDim.x) {
        const int eBase = tile * 64 + wv * 16;

        // A fragments: edge_attr[eBase+rowl][ks*16 + g*4 + j]
        bf16x4 aF[4];
        const float* ar = edge_attr + (size_t)(eBase + rowl) * 64 + g * 4;
        #pragma unroll
        for (int ks = 0; ks < 4; ++ks) {
            f32x4 v = *reinterpret_cast<const f32x4*>(ar + ks * 16);
            bf16x4 t;
            #pragma unroll
            for (int j = 0; j < 4; ++j) t[j] = f2bf(v[j]);
            aF[ks] = t;
        }

        f32x4 acc[4];
        #pragma unroll
        for (int cb = 0; cb < 4; ++cb) {
            acc[cb][0] = bias[cb]; acc[cb][1] = bias[cb];
            acc[cb][2] = bias[cb]; acc[cb][3] = bias[cb];
        }
        #pragma unroll
        for (int cb = 0; cb < 4; ++cb)
            #pragma unroll
            for (int ks = 0; ks < 4; ++ks)
                acc[cb] = __builtin_amdgcn_mfma_f32_16x16x16bf16_1k(
                    aF[ks], bF[cb][ks], acc[cb], 0, 0, 0);

        // D layout: row=(lane>>4)*4+r, col=(lane&15)+16*cb  -> LDS transpose
        #pragma unroll
        for (int cb = 0; cb < 4; ++cb)
            #pragma unroll
            for (int r = 0; r < 4; ++r)
                Elds[wv][(g * 4 + r) * 68 + rowl + 16 * cb] = acc[cb][r];
        // same-wave LDS ordering: compiler inserts lgkmcnt waits

        // Scoring: 4 edges in parallel, float4 per lane (columns 4*rowl..+3)
        const int h = rowl >> 1;     // head of this lane's 4 columns
        #pragma unroll
        for (int qi = 0; qi < 4; ++qi) {
            const int el  = qi * 4 + g;
            const int e   = eBase + el;
            const int src = ei[e];
            const int dst = ei[NE + e];
            const f32x4 Kv = *reinterpret_cast<const f32x4*>(K + (size_t)src * 64 + rowl * 4);
            const f32x4 Qv = *reinterpret_cast<const f32x4*>(Q + (size_t)dst * 64 + rowl * 4);
            const f32x4 Vv = *reinterpret_cast<const f32x4*>(V + (size_t)src * 64 + rowl * 4);
            const f32x4 El = *reinterpret_cast<const f32x4*>(&Elds[wv][el * 68 + rowl * 4]);
            f32x4 sc;
            #pragma unroll
            for (int j = 0; j < 4; ++j) sc[j] = Kv[j] * Qv[j] * El[j];
            *reinterpret_cast<f32x4*>(wE + (size_t)e * 64 + rowl * 4) = sc;
            float ss = sc[0] + sc[1] + sc[2] + sc[3];
            ss += __shfl_xor(ss, 1);            // pair covers the head's 8 cols
            float s = fminf(fmaxf(ss * inv_sqrt8, -CLAMP_V), CLAMP_V);
            float ex = __expf(s);
            if ((rowl & 1) == 0)
                atomicAdd(&den[dst * 8 + h], ex);
            #pragma unroll
            for (int j = 0; j < 4; ++j)
                atomicAdd(&Num[(size_t)dst * 64 + rowl * 4 + j], ex * (Vv[j] + sc[j]));
        }
    }
}

__global__ __launch_bounds__(256) void finalize_kernel(
    const float* __restrict__ Num, const float* __restrict__ den,
    float* __restrict__ wV)
{
    const int i = blockIdx.x * 256 + threadIdx.x;   // one float4 per thread
    if (i >= NN * 16) return;
    const int c4 = i & 15;
    const int n  = i >> 4;
    const int h  = c4 >> 1;
    const float d = den[n * 8 + h] + 1e-16f;
    f32x4 v = reinterpret_cast<const f32x4*>(Num)[i];
    v[0] /= d; v[1] /= d; v[2] /= d; v[3] /= d;
    reinterpret_cast<f32x4*>(wV)[i] = v;
}

extern "C" void kernel_launch(void* const* d_in, const int* in_sizes, int n_in,
                              void* d_out, int out_size, void* d_ws, size_t ws_size,
                              hipStream_t stream) {
    const float* x         = (const float*)d_in[0];
    const float* edge_attr = (const float*)d_in[1];
    const float* WQ        = (const float*)d_in[2];
    const float* bQ        = (const float*)d_in[3];
    const float* WK        = (const float*)d_in[4];
    const float* WVw       = (const float*)d_in[5];
    const float* WE1       = (const float*)d_in[6];
    const float* bE1       = (const float*)d_in[7];
    const int*   ei        = (const int*)d_in[8];

    float* out = (float*)d_out;
    float* wV = out;                          // [NN, 64]
    float* wE = out + (size_t)NN * 64;        // [NE, 64]

    float* Q   = (float*)d_ws;                // [NN,64]
    float* K   = Q + (size_t)NN * 64;         // [NN,64]
    float* V   = K + (size_t)NN * 64;         // [NN,64]
    float* den = V + (size_t)NN * 64;         // [NN,8]
    float* Num = den + (size_t)NN * 8;        // [NN,64]

    hipMemsetAsync(den, 0, (size_t)NN * 8  * sizeof(float), stream);
    hipMemsetAsync(Num, 0, (size_t)NN * 64 * sizeof(float), stream);

    proj_kernel<<<2048, 256, 0, stream>>>(x, WQ, bQ, WK, WVw, Q, K, V);
    edge_fused_kernel<<<2048, 256, 0, stream>>>(edge_attr, WE1, bE1, ei, Q, K, V,
                                                wE, den, Num);
    finalize_kernel<<<(NN * 16 + 255) / 256, 256, 0, stream>>>(Num, den, wV);
}

// Round 6
// 518.344 us; speedup vs baseline: 2.9827x; 2.9827x over previous
//
#include <hip/hip_runtime.h>

#define NN 50000
#define NE 1600000
#define CLAMP_V 5.0f

typedef __attribute__((ext_vector_type(4))) short bf16x4;
typedef __attribute__((ext_vector_type(4))) float f32x4;

static __device__ __forceinline__ short f2bf(float x) {
    unsigned u = __builtin_bit_cast(unsigned, x);
    u += 0x7FFF + ((u >> 16) & 1);   // round-to-nearest-even
    return (short)(u >> 16);
}

__global__ __launch_bounds__(256) void proj_kernel(
    const float* __restrict__ x,
    const float* __restrict__ WQ, const float* __restrict__ bQ,
    const float* __restrict__ WK, const float* __restrict__ WVw,
    float* __restrict__ Q, float* __restrict__ K, float* __restrict__ V)
{
    __shared__ float sWQ[4096], sWK[4096], sWV[4096];
    for (int i = threadIdx.x; i < 4096; i += 256) {
        sWQ[i] = WQ[i]; sWK[i] = WK[i]; sWV[i] = WVw[i];
    }
    __syncthreads();
    const int col = threadIdx.x & 63;
    const int nl  = threadIdx.x >> 6;
    const float bq = bQ[col];
    for (int node = blockIdx.x * 4 + nl; node < NN; node += gridDim.x * 4) {
        const float* xr = x + (size_t)node * 64;
        float aq = 0.f, ak = 0.f, av = 0.f;
        #pragma unroll
        for (int j = 0; j < 64; ++j) {
            float xv = xr[j];
            aq = fmaf(xv, sWQ[j*64+col], aq);
            ak = fmaf(xv, sWK[j*64+col], ak);
            av = fmaf(xv, sWV[j*64+col], av);
        }
        Q[(size_t)node*64+col] = aq + bq;
        K[(size_t)node*64+col] = ak;
        V[(size_t)node*64+col] = av;
    }
}

// Fused edge pass. Vectorized gather/score (4 edges x float4-per-lane),
// atomics restored to lane=column layout via LDS transpose:
//  E = edge_attr @ WE1 + bE1 (MFMA), sc = K[src]*Q[dst]*E -> wE,
//  ex = exp(clamp(sum_head(sc)/sqrt8)), den[dst,h] += ex,
//  Num[dst,c]   += ex*(V[src,c]+sc)   (256B-contiguous atomic per edge)
__global__ __launch_bounds__(256) void edge_fused_kernel(
    const float* __restrict__ edge_attr,
    const float* __restrict__ WE1, const float* __restrict__ bE1,
    const int* __restrict__ ei,
    const float* __restrict__ Q, const float* __restrict__ K,
    const float* __restrict__ V,
    float* __restrict__ wE, float* __restrict__ den, float* __restrict__ Num)
{
    __shared__ float Elds[4][16 * 64];   // [wave][edge][col] E tile
    __shared__ float Plds[4][16 * 64];   // [wave][edge][col] ex*(V+sc)
    const int tid  = threadIdx.x;
    const int wv   = tid >> 6;
    const int lane = tid & 63;
    const int g    = lane >> 4;      // k-group (MFMA) / edge-in-quad (scoring)
    const int rowl = lane & 15;      // A-row (MFMA) / col-quad (scoring)

    // B fragments of WE1 (bf16) + bias. B[k=(ks*16 + g*4 + j)][col]
    bf16x4 bF[4][4];
    float  bias[4];
    #pragma unroll
    for (int cb = 0; cb < 4; ++cb) {
        const int col = rowl + 16 * cb;
        bias[cb] = bE1[col];
        #pragma unroll
        for (int ks = 0; ks < 4; ++ks) {
            bf16x4 t;
            #pragma unroll
            for (int j = 0; j < 4; ++j)
                t[j] = f2bf(WE1[(ks * 16 + g * 4 + j) * 64 + col]);
            bF[cb][ks] = t;
        }
    }

    const float inv_sqrt8 = 0.35355339059327373f;

    for (int tile = blockIdx.x; tile < (NE / 64); tile += gridDim.x) {
        const int eBase = tile * 64 + wv * 16;

        // preload src/dst for this wave's 16 edges (lane rowl holds edge rowl)
        const int srcv = ei[eBase + rowl];
        const int dstv = ei[NE + eBase + rowl];

        // A fragments: edge_attr[eBase+rowl][ks*16 + g*4 + j]
        bf16x4 aF[4];
        const float* ar = edge_attr + (size_t)(eBase + rowl) * 64 + g * 4;
        #pragma unroll
        for (int ks = 0; ks < 4; ++ks) {
            f32x4 v = *reinterpret_cast<const f32x4*>(ar + ks * 16);
            bf16x4 t;
            #pragma unroll
            for (int j = 0; j < 4; ++j) t[j] = f2bf(v[j]);
            aF[ks] = t;
        }

        f32x4 acc[4];
        #pragma unroll
        for (int cb = 0; cb < 4; ++cb) {
            acc[cb][0] = bias[cb]; acc[cb][1] = bias[cb];
            acc[cb][2] = bias[cb]; acc[cb][3] = bias[cb];
        }
        #pragma unroll
        for (int cb = 0; cb < 4; ++cb)
            #pragma unroll
            for (int ks = 0; ks < 4; ++ks)
                acc[cb] = __builtin_amdgcn_mfma_f32_16x16x16bf16_1k(
                    aF[ks], bF[cb][ks], acc[cb], 0, 0, 0);

        // D layout: row=(lane>>4)*4+r, col=(lane&15)+16*cb  -> LDS transpose
        #pragma unroll
        for (int cb = 0; cb < 4; ++cb)
            #pragma unroll
            for (int r = 0; r < 4; ++r)
                Elds[wv][(g * 4 + r) * 64 + rowl + 16 * cb] = acc[cb][r];
        // same-wave LDS ordering: compiler inserts lgkmcnt waits

        // Scoring: 4 edges in parallel, float4 per lane (cols 4*rowl..+3)
        const int h = rowl >> 1;     // head of this lane's 4 columns
        #pragma unroll
        for (int qi = 0; qi < 4; ++qi) {
            const int el  = qi * 4 + g;
            const int e   = eBase + el;
            const int src = __shfl(srcv, el);
            const int dst = __shfl(dstv, el);
            const f32x4 Kv = *reinterpret_cast<const f32x4*>(K + (size_t)src * 64 + rowl * 4);
            const f32x4 Qv = *reinterpret_cast<const f32x4*>(Q + (size_t)dst * 64 + rowl * 4);
            const f32x4 Vv = *reinterpret_cast<const f32x4*>(V + (size_t)src * 64 + rowl * 4);
            const f32x4 El = *reinterpret_cast<const f32x4*>(&Elds[wv][el * 64 + rowl * 4]);
            f32x4 sc;
            #pragma unroll
            for (int j = 0; j < 4; ++j) sc[j] = Kv[j] * Qv[j] * El[j];
            *reinterpret_cast<f32x4*>(wE + (size_t)e * 64 + rowl * 4) = sc;
            float ss = sc[0] + sc[1] + sc[2] + sc[3];
            ss += __shfl_xor(ss, 1);            // pair covers the head's 8 cols
            float s = fminf(fmaxf(ss * inv_sqrt8, -CLAMP_V), CLAMP_V);
            float ex = __expf(s);
            if ((rowl & 1) == 0)
                atomicAdd(&den[dst * 8 + h], ex);
            f32x4 t;
            #pragma unroll
            for (int j = 0; j < 4; ++j) t[j] = ex * (Vv[j] + sc[j]);
            *reinterpret_cast<f32x4*>(&Plds[wv][el * 64 + rowl * 4]) = t;
        }

        // Atomic phase: one 256B-contiguous atomic instruction per edge
        #pragma unroll
        for (int el = 0; el < 16; ++el) {
            const int dst = __shfl(dstv, el);
            atomicAdd(&Num[(size_t)dst * 64 + lane], Plds[wv][el * 64 + lane]);
        }
    }
}

__global__ __launch_bounds__(256) void finalize_kernel(
    const float* __restrict__ Num, const float* __restrict__ den,
    float* __restrict__ wV)
{
    const int i = blockIdx.x * 256 + threadIdx.x;   // one float4 per thread
    if (i >= NN * 16) return;
    const int c4 = i & 15;
    const int n  = i >> 4;
    const int h  = c4 >> 1;
    const float d = den[n * 8 + h] + 1e-16f;
    f32x4 v = reinterpret_cast<const f32x4*>(Num)[i];
    v[0] /= d; v[1] /= d; v[2] /= d; v[3] /= d;
    reinterpret_cast<f32x4*>(wV)[i] = v;
}

extern "C" void kernel_launch(void* const* d_in, const int* in_sizes, int n_in,
                              void* d_out, int out_size, void* d_ws, size_t ws_size,
                              hipStream_t stream) {
    const float* x         = (const float*)d_in[0];
    const float* edge_attr = (const float*)d_in[1];
    const float* WQ        = (const float*)d_in[2];
    const float* bQ        = (const float*)d_in[3];
    const float* WK        = (const float*)d_in[4];
    const float* WVw       = (const float*)d_in[5];
    const float* WE1       = (const float*)d_in[6];
    const float* bE1       = (const float*)d_in[7];
    const int*   ei        = (const int*)d_in[8];

    float* out = (float*)d_out;
    float* wV = out;                          // [NN, 64]
    float* wE = out + (size_t)NN * 64;        // [NE, 64]

    float* Q   = (float*)d_ws;                // [NN,64]
    float* K   = Q + (size_t)NN * 64;         // [NN,64]
    float* V   = K + (size_t)NN * 64;         // [NN,64]
    float* den = V + (size_t)NN * 64;         // [NN,8]
    float* Num = den + (size_t)NN * 8;        // [NN,64]

    hipMemsetAsync(den, 0, (size_t)NN * 8  * sizeof(float), stream);
    hipMemsetAsync(Num, 0, (size_t)NN * 64 * sizeof(float), stream);

    proj_kernel<<<2048, 256, 0, stream>>>(x, WQ, bQ, WK, WVw, Q, K, V);
    edge_fused_kernel<<<2048, 256, 0, stream>>>(edge_attr, WE1, bE1, ei, Q, K, V,
                                                wE, den, Num);
    finalize_kernel<<<(NN * 16 + 255) / 256, 256, 0, stream>>>(Num, den, wV);
}

// Round 7
// 508.290 us; speedup vs baseline: 3.0417x; 1.0198x over previous
//
#include <hip/hip_runtime.h>

#define NN 50000
#define NE 1600000
#define CLAMP_V 5.0f

typedef __attribute__((ext_vector_type(4))) short bf16x4;
typedef __attribute__((ext_vector_type(4))) float f32x4;

static __device__ __forceinline__ short f2bf(float x) {
    unsigned u = __builtin_bit_cast(unsigned, x);
    u += 0x7FFF + ((u >> 16) & 1);   // round-to-nearest-even
    return (short)(u >> 16);
}

__global__ __launch_bounds__(256) void proj_kernel(
    const float* __restrict__ x,
    const float* __restrict__ WQ, const float* __restrict__ bQ,
    const float* __restrict__ WK, const float* __restrict__ WVw,
    float* __restrict__ Q, float* __restrict__ K, float* __restrict__ V)
{
    __shared__ float sWQ[4096], sWK[4096], sWV[4096];
    for (int i = threadIdx.x; i < 4096; i += 256) {
        sWQ[i] = WQ[i]; sWK[i] = WK[i]; sWV[i] = WVw[i];
    }
    __syncthreads();
    const int col = threadIdx.x & 63;
    const int nl  = threadIdx.x >> 6;
    const float bq = bQ[col];
    for (int node = blockIdx.x * 4 + nl; node < NN; node += gridDim.x * 4) {
        const float* xr = x + (size_t)node * 64;
        float aq = 0.f, ak = 0.f, av = 0.f;
        #pragma unroll
        for (int j = 0; j < 64; ++j) {
            float xv = xr[j];
            aq = fmaf(xv, sWQ[j*64+col], aq);
            ak = fmaf(xv, sWK[j*64+col], ak);
            av = fmaf(xv, sWV[j*64+col], av);
        }
        Q[(size_t)node*64+col] = aq + bq;
        K[(size_t)node*64+col] = ak;
        V[(size_t)node*64+col] = av;
    }
}

// Fused edge pass. Vectorized gather/score (4 edges x float4-per-lane),
// atomics in lane=column layout via in-place LDS transpose (P overwrites E):
//  E = edge_attr @ WE1 + bE1 (MFMA), sc = K[src]*Q[dst]*E -> wE (nontemporal),
//  ex = exp(clamp(sum_head(sc)/sqrt8)), den[dst,h] += ex,
//  Num[dst,c] += ex*(V[src,c]+sc)   (256B-contiguous atomic per edge)
__global__ __launch_bounds__(256) void edge_fused_kernel(
    const float* __restrict__ edge_attr,
    const float* __restrict__ WE1, const float* __restrict__ bE1,
    const int* __restrict__ ei,
    const float* __restrict__ Q, const float* __restrict__ K,
    const float* __restrict__ V,
    float* __restrict__ wE, float* __restrict__ den, float* __restrict__ Num)
{
    __shared__ float Elds[4][16 * 64];   // [wave][edge][col]: E tile, then P in-place
    const int tid  = threadIdx.x;
    const int wv   = tid >> 6;
    const int lane = tid & 63;
    const int g    = lane >> 4;      // k-group (MFMA) / edge-in-quad (scoring)
    const int rowl = lane & 15;      // A-row (MFMA) / col-quad (scoring)

    // B fragments of WE1 (bf16) + bias. B[k=(ks*16 + g*4 + j)][col]
    bf16x4 bF[4][4];
    float  bias[4];
    #pragma unroll
    for (int cb = 0; cb < 4; ++cb) {
        const int col = rowl + 16 * cb;
        bias[cb] = bE1[col];
        #pragma unroll
        for (int ks = 0; ks < 4; ++ks) {
            bf16x4 t;
            #pragma unroll
            for (int j = 0; j < 4; ++j)
                t[j] = f2bf(WE1[(ks * 16 + g * 4 + j) * 64 + col]);
            bF[cb][ks] = t;
        }
    }

    const float inv_sqrt8 = 0.35355339059327373f;

    for (int tile = blockIdx.x; tile < (NE / 64); tile += gridDim.x) {
        const int eBase = tile * 64 + wv * 16;

        // preload src/dst for this wave's 16 edges (lane rowl holds edge rowl)
        const int srcv = ei[eBase + rowl];
        const int dstv = ei[NE + eBase + rowl];

        // A fragments: edge_attr[eBase+rowl][ks*16 + g*4 + j] (nontemporal stream)
        bf16x4 aF[4];
        const float* ar = edge_attr + (size_t)(eBase + rowl) * 64 + g * 4;
        #pragma unroll
        for (int ks = 0; ks < 4; ++ks) {
            f32x4 v = __builtin_nontemporal_load(
                reinterpret_cast<const f32x4*>(ar + ks * 16));
            bf16x4 t;
            #pragma unroll
            for (int j = 0; j < 4; ++j) t[j] = f2bf(v[j]);
            aF[ks] = t;
        }

        f32x4 acc[4];
        #pragma unroll
        for (int cb = 0; cb < 4; ++cb) {
            acc[cb][0] = bias[cb]; acc[cb][1] = bias[cb];
            acc[cb][2] = bias[cb]; acc[cb][3] = bias[cb];
        }
        #pragma unroll
        for (int cb = 0; cb < 4; ++cb)
            #pragma unroll
            for (int ks = 0; ks < 4; ++ks)
                acc[cb] = __builtin_amdgcn_mfma_f32_16x16x16bf16_1k(
                    aF[ks], bF[cb][ks], acc[cb], 0, 0, 0);

        // D layout: row=(lane>>4)*4+r, col=(lane&15)+16*cb  -> LDS transpose
        #pragma unroll
        for (int cb = 0; cb < 4; ++cb)
            #pragma unroll
            for (int r = 0; r < 4; ++r)
                Elds[wv][(g * 4 + r) * 64 + rowl + 16 * cb] = acc[cb][r];
        // same-wave LDS ordering: compiler inserts lgkmcnt waits

        // Scoring: 4 edges in parallel, float4 per lane (cols 4*rowl..+3).
        // Each lane reads its 16B of E and overwrites it with P = ex*(V+sc).
        const int h = rowl >> 1;     // head of this lane's 4 columns
        #pragma unroll
        for (int qi = 0; qi < 4; ++qi) {
            const int el  = qi * 4 + g;
            const int e   = eBase + el;
            const int src = __shfl(srcv, el);
            const int dst = __shfl(dstv, el);
            const f32x4 Kv = *reinterpret_cast<const f32x4*>(K + (size_t)src * 64 + rowl * 4);
            const f32x4 Qv = *reinterpret_cast<const f32x4*>(Q + (size_t)dst * 64 + rowl * 4);
            const f32x4 Vv = *reinterpret_cast<const f32x4*>(V + (size_t)src * 64 + rowl * 4);
            f32x4* eslot = reinterpret_cast<f32x4*>(&Elds[wv][el * 64 + rowl * 4]);
            const f32x4 El = *eslot;
            f32x4 sc;
            #pragma unroll
            for (int j = 0; j < 4; ++j) sc[j] = Kv[j] * Qv[j] * El[j];
            __builtin_nontemporal_store(sc,
                reinterpret_cast<f32x4*>(wE + (size_t)e * 64 + rowl * 4));
            float ss = sc[0] + sc[1] + sc[2] + sc[3];
            ss += __shfl_xor(ss, 1);            // pair covers the head's 8 cols
            float s = fminf(fmaxf(ss * inv_sqrt8, -CLAMP_V), CLAMP_V);
            float ex = __expf(s);
            if ((rowl & 1) == 0)
                atomicAdd(&den[dst * 8 + h], ex);
            f32x4 t;
            #pragma unroll
            for (int j = 0; j < 4; ++j) t[j] = ex * (Vv[j] + sc[j]);
            *eslot = t;                          // P in-place over E
        }

        // Atomic phase: one 256B-contiguous atomic instruction per edge
        #pragma unroll
        for (int el = 0; el < 16; ++el) {
            const int dst = __shfl(dstv, el);
            atomicAdd(&Num[(size_t)dst * 64 + lane], Elds[wv][el * 64 + lane]);
        }
    }
}

__global__ __launch_bounds__(256) void finalize_kernel(
    const float* __restrict__ Num, const float* __restrict__ den,
    float* __restrict__ wV)
{
    const int i = blockIdx.x * 256 + threadIdx.x;   // one float4 per thread
    if (i >= NN * 16) return;
    const int c4 = i & 15;
    const int n  = i >> 4;
    const int h  = c4 >> 1;
    const float d = den[n * 8 + h] + 1e-16f;
    f32x4 v = reinterpret_cast<const f32x4*>(Num)[i];
    v[0] /= d; v[1] /= d; v[2] /= d; v[3] /= d;
    reinterpret_cast<f32x4*>(wV)[i] = v;
}

extern "C" void kernel_launch(void* const* d_in, const int* in_sizes, int n_in,
                              void* d_out, int out_size, void* d_ws, size_t ws_size,
                              hipStream_t stream) {
    const float* x         = (const float*)d_in[0];
    const float* edge_attr = (const float*)d_in[1];
    const float* WQ        = (const float*)d_in[2];
    const float* bQ        = (const float*)d_in[3];
    const float* WK        = (const float*)d_in[4];
    const float* WVw       = (const float*)d_in[5];
    const float* WE1       = (const float*)d_in[6];
    const float* bE1       = (const float*)d_in[7];
    const int*   ei        = (const int*)d_in[8];

    float* out = (float*)d_out;
    float* wV = out;                          // [NN, 64]
    float* wE = out + (size_t)NN * 64;        // [NE, 64]

    float* Q   = (float*)d_ws;                // [NN,64]
    float* K   = Q + (size_t)NN * 64;         // [NN,64]
    float* V   = K + (size_t)NN * 64;         // [NN,64]
    float* den = V + (size_t)NN * 64;         // [NN,8]
    float* Num = den + (size_t)NN * 8;        // [NN,64]

    hipMemsetAsync(den, 0, (size_t)NN * 8  * sizeof(float), stream);
    hipMemsetAsync(Num, 0, (size_t)NN * 64 * sizeof(float), stream);

    proj_kernel<<<2048, 256, 0, stream>>>(x, WQ, bQ, WK, WVw, Q, K, V);
    edge_fused_kernel<<<2048, 256, 0, stream>>>(edge_attr, WE1, bE1, ei, Q, K, V,
                                                wE, den, Num);
    finalize_kernel<<<(NN * 16 + 255) / 256, 256, 0, stream>>>(Num, den, wV);
}